// Round 3
// baseline (1113.611 us; speedup 1.0000x reference)
//
#include <hip/hip_runtime.h>

// Problem constants
#define N_NODES 50000
#define N_EDGES 600000
#define NPAD    50048          // 782*64 = 391*128, padded row count for tiled GEMMs
#define NBLK_SCAN 196          // ceil(50000/256)

static __device__ __forceinline__ float lrelu(float v) {
    return v > 0.f ? v : 0.01f * v;
}

// ---------------------------------------------------------------------------
// proj768_v3: [N,768] @ [768,NCOLS], in-block split-K=4.
// Block = 256 threads = 4 waves; wave w handles K-quarter w (kh wave-uniform
// so W loads stay scalar/SGPR), lane = row (64 rows/block). Partials reduced
// through LDS; bias+lrelu fused into the store. No global partials.
// ---------------------------------------------------------------------------
template<int NCOLS>
__global__ __launch_bounds__(256) void proj768_v3(
    const float* __restrict__ A, const float* __restrict__ W,
    const float* __restrict__ bias, int coff, float* __restrict__ X0)
{
    constexpr int PAD = (NCOLS % 2 == 0) ? NCOLS + 1 : NCOLS;  // odd stride: conflict-free
    __shared__ float red[4 * 64 * PAD];
    const int t    = threadIdx.x;
    const int lane = t & 63;
    const int kh   = t >> 6;               // wave-uniform K quarter
    const int r0   = blockIdx.x * 64;
    const int row  = r0 + lane;
    const int rowc = row < N_NODES ? row : N_NODES - 1;   // clamp, skip store later

    float acc[NCOLS];
    #pragma unroll
    for (int c = 0; c < NCOLS; c++) acc[c] = 0.f;

    const float4* Ar = (const float4*)(A + (size_t)rowc * 768 + kh * 192);
    const float*  Wp = W + (size_t)kh * 192 * NCOLS;

    #pragma unroll 2
    for (int j = 0; j < 48; j++) {
        float4 a = Ar[j];
        const float* w = Wp + j * 4 * NCOLS;
        #pragma unroll
        for (int c = 0; c < NCOLS; c++)
            acc[c] += a.x * w[c] + a.y * w[NCOLS + c]
                    + a.z * w[2 * NCOLS + c] + a.w * w[3 * NCOLS + c];
    }

    float* rd = &red[(kh * 64 + lane) * PAD];
    #pragma unroll
    for (int c = 0; c < NCOLS; c++) rd[c] = acc[c];
    __syncthreads();

    // Reduce 4 partials: thread -> (c = t&31, row base = t>>5), 8 rows each.
    const int c  = t & 31;
    const int rb = t >> 5;
    if (c < NCOLS) {
        float bc = bias[c];
        #pragma unroll
        for (int rr = 0; rr < 8; rr++) {
            int r = rb + rr * 8;
            float s = red[(0 * 64 + r) * PAD + c] + red[(1 * 64 + r) * PAD + c]
                    + red[(2 * 64 + r) * PAD + c] + red[(3 * 64 + r) * PAD + c];
            int n = r0 + r;
            if (n < N_NODES)
                X0[(size_t)n * 128 + coff + c] = lrelu(s + bc);
        }
    }
}

// ---------------------------------------------------------------------------
// Small projections: num (K=7 -> cols 53..77), cat (K=11 -> 78..102),
// new_feature (K=1 -> 103..127). One thread per (node, out-col).
// ---------------------------------------------------------------------------
__global__ void small_proj_kernel(
    const float* __restrict__ nump, const float* __restrict__ catp, const float* __restrict__ newf,
    const float* __restrict__ Wn, const float* __restrict__ bn,
    const float* __restrict__ Wc, const float* __restrict__ bc,
    const float* __restrict__ Ww, const float* __restrict__ bw,
    float* __restrict__ out)
{
    int id = blockIdx.x * 256 + threadIdx.x;
    int n = id / 75, c = id % 75;
    if (n >= N_NODES) return;
    float acc; int col;
    if (c < 25) {
        col = 53 + c; acc = bn[c];
        #pragma unroll
        for (int k = 0; k < 7; k++) acc += nump[n * 7 + k] * Wn[k * 25 + c];
    } else if (c < 50) {
        int cc = c - 25; col = 78 + cc; acc = bc[cc];
        #pragma unroll
        for (int k = 0; k < 11; k++) acc += catp[n * 11 + k] * Wc[k * 25 + cc];
    } else {
        int cc = c - 50; col = 103 + cc;
        acc = bw[cc] + newf[n] * Ww[cc];
    }
    out[(size_t)n * 128 + col] = lrelu(acc);
}

// ---------------------------------------------------------------------------
// gemm_v2: tiled fp32 GEMM, 128 out cols. Tile 128 rows x 128 cols, K-tile 32.
// 256 threads as 16x16, 8x8 micro-tile. A stored TRANSPOSED in LDS so the
// inner loop is pure ds_read_b128.
// SPLIT: A = [S (256 wide) | A2 (128 wide)], B = [rel_w (256 rows); root_w].
// ---------------------------------------------------------------------------
template<int KTOT, bool SPLIT, bool ACT>
__global__ __launch_bounds__(256, 4) void gemm_v2(
    const float* __restrict__ A, const float* __restrict__ A2,
    const float* __restrict__ B, const float* __restrict__ B2,
    const float* __restrict__ bias, float* __restrict__ out)
{
    __shared__ float AlT[32 * 132];   // [k][row], row-padded stride 132
    __shared__ float Bl [32 * 132];   // [k][col]
    const int t  = threadIdx.x;
    const int r0 = blockIdx.x * 128;
    const int tx = t & 15, ty = t >> 4;

    float acc[8][8] = {};

    for (int k0 = 0; k0 < KTOT; k0 += 32) {
        // A tile: 128 rows x 32 k = 1024 float4, 4 per thread, store transposed
        #pragma unroll
        for (int i = 0; i < 4; i++) {
            int f4i = t + i * 256;
            int row = f4i >> 3, c4 = f4i & 7;
            int k = k0 + c4 * 4;
            float4 v;
            if (!SPLIT) {
                v = *(const float4*)&A[(size_t)(r0 + row) * 128 + k];
            } else {
                if (k < 256) v = *(const float4*)&A[(size_t)(r0 + row) * 256 + k];
                else         v = *(const float4*)&A2[(size_t)(r0 + row) * 128 + (k - 256)];
            }
            AlT[(c4 * 4 + 0) * 132 + row] = v.x;
            AlT[(c4 * 4 + 1) * 132 + row] = v.y;
            AlT[(c4 * 4 + 2) * 132 + row] = v.z;
            AlT[(c4 * 4 + 3) * 132 + row] = v.w;
        }
        // B tile: 32 k x 128 cols = 1024 float4, 4 per thread
        #pragma unroll
        for (int i = 0; i < 4; i++) {
            int f4i = t + i * 256;
            int kk = f4i >> 5, c4 = f4i & 31;
            int k = k0 + kk;
            float4 v;
            if (!SPLIT) v = *(const float4*)&B[(size_t)k * 128 + c4 * 4];
            else v = (k < 256) ? *(const float4*)&B[(size_t)k * 128 + c4 * 4]
                               : *(const float4*)&B2[(size_t)(k - 256) * 128 + c4 * 4];
            *(float4*)&Bl[kk * 132 + c4 * 4] = v;
        }
        __syncthreads();
        #pragma unroll 4
        for (int k = 0; k < 32; k++) {
            float4 a0 = *(const float4*)&AlT[k * 132 + ty * 8];
            float4 a1 = *(const float4*)&AlT[k * 132 + ty * 8 + 4];
            float4 b0 = *(const float4*)&Bl [k * 132 + tx * 8];
            float4 b1 = *(const float4*)&Bl [k * 132 + tx * 8 + 4];
            float av[8] = {a0.x, a0.y, a0.z, a0.w, a1.x, a1.y, a1.z, a1.w};
            float bv[8] = {b0.x, b0.y, b0.z, b0.w, b1.x, b1.y, b1.z, b1.w};
            #pragma unroll
            for (int i = 0; i < 8; i++)
                #pragma unroll
                for (int j = 0; j < 8; j++) acc[i][j] += av[i] * bv[j];
        }
        __syncthreads();
    }
    float4 bb0 = *(const float4*)&bias[tx * 8];
    float4 bb1 = *(const float4*)&bias[tx * 8 + 4];
    float bb[8] = {bb0.x, bb0.y, bb0.z, bb0.w, bb1.x, bb1.y, bb1.z, bb1.w};
    #pragma unroll
    for (int i = 0; i < 8; i++) {
        size_t row = (size_t)(r0 + ty * 8 + i);
        float o[8];
        #pragma unroll
        for (int j = 0; j < 8; j++) {
            o[j] = acc[i][j] + bb[j];
            if (ACT) o[j] = lrelu(o[j]);
        }
        *(float4*)&out[row * 128 + tx * 8]     = make_float4(o[0], o[1], o[2], o[3]);
        *(float4*)&out[row * 128 + tx * 8 + 4] = make_float4(o[4], o[5], o[6], o[7]);
    }
}

// ---------------------------------------------------------------------------
// CSR build: count, 3-phase exclusive scan, fill (type packed into sign bit).
// ---------------------------------------------------------------------------
__global__ void count_kernel(const int* __restrict__ ei, int* __restrict__ count) {
    int e = blockIdx.x * 256 + threadIdx.x;
    if (e < N_EDGES) atomicAdd(&count[ei[N_EDGES + e]], 1);
}

__global__ void scan1_kernel(const int* __restrict__ count, int* __restrict__ partial) {
    __shared__ int sm[256];
    int b = blockIdx.x, t = threadIdx.x;
    int i = b * 256 + t;
    sm[t] = (i < N_NODES) ? count[i] : 0;
    __syncthreads();
    for (int off = 128; off > 0; off >>= 1) {
        if (t < off) sm[t] += sm[t + off];
        __syncthreads();
    }
    if (t == 0) partial[b] = sm[0];
}

__global__ void scan2_kernel(int* __restrict__ partial) {
    __shared__ int sm[256];
    int t = threadIdx.x;
    int v = (t < NBLK_SCAN) ? partial[t] : 0;
    sm[t] = v; __syncthreads();
    for (int off = 1; off < 256; off <<= 1) {
        int add = (t >= off) ? sm[t - off] : 0;
        __syncthreads();
        sm[t] += add;
        __syncthreads();
    }
    partial[t] = sm[t] - v;   // exclusive
}

__global__ void scan3_kernel(const int* __restrict__ count, const int* __restrict__ partial,
                             int* __restrict__ offsets) {
    __shared__ int sm[256];
    int b = blockIdx.x, t = threadIdx.x;
    int i = b * 256 + t;
    int v = (i < N_NODES) ? count[i] : 0;
    sm[t] = v; __syncthreads();
    for (int off = 1; off < 256; off <<= 1) {
        int add = (t >= off) ? sm[t - off] : 0;
        __syncthreads();
        sm[t] += add;
        __syncthreads();
    }
    if (i < N_NODES) offsets[i] = partial[b] + sm[t] - v;
}

__global__ void fill_kernel(const int* __restrict__ ei, const int* __restrict__ et,
                            const int* __restrict__ offsets, int* __restrict__ cursor,
                            int* __restrict__ elist) {
    int e = blockIdx.x * 256 + threadIdx.x;
    if (e < N_EDGES) {
        int d = ei[N_EDGES + e];
        int pos = atomicAdd(&cursor[d], 1);
        elist[offsets[d] + pos] = (int)(((unsigned)ei[e]) | (((unsigned)et[e]) << 31));
    }
}

// ---------------------------------------------------------------------------
// aggregate_v3: s[n][r][:] = (1/max(deg,1)) * sum_{e:type=r} x[src_e][:]
// 32 lanes per node (float4 each), 8 nodes per 256-thread block.
// 2-edge unroll for memory-level parallelism.
// ---------------------------------------------------------------------------
__global__ __launch_bounds__(256) void aggregate_v3(
    const float* __restrict__ x, const int* __restrict__ offsets,
    const int* __restrict__ count, const int* __restrict__ elist,
    float* __restrict__ s)
{
    int nid  = blockIdx.x * 8 + (threadIdx.x >> 5);
    int lane = threadIdx.x & 31;
    if (nid >= N_NODES) return;
    int start = offsets[nid], dg = count[nid];
    float4 a0 = make_float4(0.f, 0.f, 0.f, 0.f);
    float4 a1 = make_float4(0.f, 0.f, 0.f, 0.f);
    int i = 0;
    for (; i + 2 <= dg; i += 2) {
        int v0 = elist[start + i];
        int v1 = elist[start + i + 1];
        float4 u = ((const float4*)&x[(size_t)(v0 & 0x7FFFFFFF) * 128])[lane];
        float4 w = ((const float4*)&x[(size_t)(v1 & 0x7FFFFFFF) * 128])[lane];
        if (v0 < 0) { a1.x += u.x; a1.y += u.y; a1.z += u.z; a1.w += u.w; }
        else        { a0.x += u.x; a0.y += u.y; a0.z += u.z; a0.w += u.w; }
        if (v1 < 0) { a1.x += w.x; a1.y += w.y; a1.z += w.z; a1.w += w.w; }
        else        { a0.x += w.x; a0.y += w.y; a0.z += w.z; a0.w += w.w; }
    }
    if (i < dg) {
        int v0 = elist[start + i];
        float4 u = ((const float4*)&x[(size_t)(v0 & 0x7FFFFFFF) * 128])[lane];
        if (v0 < 0) { a1.x += u.x; a1.y += u.y; a1.z += u.z; a1.w += u.w; }
        else        { a0.x += u.x; a0.y += u.y; a0.z += u.z; a0.w += u.w; }
    }
    float inv = 1.0f / (float)(dg > 0 ? dg : 1);
    a0.x *= inv; a0.y *= inv; a0.z *= inv; a0.w *= inv;
    a1.x *= inv; a1.y *= inv; a1.z *= inv; a1.w *= inv;
    ((float4*)&s[(size_t)nid * 256])[lane]       = a0;
    ((float4*)&s[(size_t)nid * 256 + 128])[lane] = a1;
}

// ---------------------------------------------------------------------------
// Final: out[n][0:2] = x4[n] @ W_out2 + b_out2. One wave per node.
// ---------------------------------------------------------------------------
__global__ __launch_bounds__(64) void final_kernel(
    const float* __restrict__ x, const float* __restrict__ W2,
    const float* __restrict__ b2, float* __restrict__ out)
{
    int n = blockIdx.x;
    int t = threadIdx.x;
    float x0 = x[(size_t)n * 128 + t];
    float x1 = x[(size_t)n * 128 + 64 + t];
    float p0 = x0 * W2[t * 2]     + x1 * W2[(t + 64) * 2];
    float p1 = x0 * W2[t * 2 + 1] + x1 * W2[(t + 64) * 2 + 1];
    #pragma unroll
    for (int off = 32; off > 0; off >>= 1) {
        p0 += __shfl_down(p0, off);
        p1 += __shfl_down(p1, off);
    }
    if (t == 0) {
        out[(size_t)n * 2]     = p0 + b2[0];
        out[(size_t)n * 2 + 1] = p1 + b2[1];
    }
}

// ---------------------------------------------------------------------------
extern "C" void kernel_launch(void* const* d_in, const int* in_sizes, int n_in,
                              void* d_out, int out_size, void* d_ws, size_t ws_size,
                              hipStream_t stream)
{
    const float* des   = (const float*)d_in[0];
    const float* tw    = (const float*)d_in[1];
    const float* nump  = (const float*)d_in[2];
    const float* catp  = (const float*)d_in[3];
    const float* newf  = (const float*)d_in[4];
    const int*   ei    = (const int*)d_in[5];
    const int*   et    = (const int*)d_in[6];
    const float* Wd    = (const float*)d_in[7];  const float* bd  = (const float*)d_in[8];
    const float* Wt    = (const float*)d_in[9];  const float* bt  = (const float*)d_in[10];
    const float* Wn    = (const float*)d_in[11]; const float* bn  = (const float*)d_in[12];
    const float* Wc    = (const float*)d_in[13]; const float* bc  = (const float*)d_in[14];
    const float* Ww    = (const float*)d_in[15]; const float* bw  = (const float*)d_in[16];
    const float* Win   = (const float*)d_in[17]; const float* bin = (const float*)d_in[18];
    const float* relw1 = (const float*)d_in[19]; const float* rootw1 = (const float*)d_in[20];
    const float* bias1 = (const float*)d_in[21];
    const float* relw2 = (const float*)d_in[22]; const float* rootw2 = (const float*)d_in[23];
    const float* bias2 = (const float*)d_in[24];
    const float* Wo1   = (const float*)d_in[25]; const float* bo1 = (const float*)d_in[26];
    const float* Wo2   = (const float*)d_in[27]; const float* bo2 = (const float*)d_in[28];
    float* outp = (float*)d_out;

    // Workspace layout (~106 MB)
    char* ws = (char*)d_ws;
    const size_t szX = (size_t)NPAD * 128 * sizeof(float);
    float* X0 = (float*)(ws);
    float* X1 = (float*)(ws + szX);
    float* S  = (float*)(ws + 2 * szX);          // NPAD*256 floats (51.2 MB)
    char* p = ws + 2 * szX + (size_t)NPAD * 256 * sizeof(float);
    int* count   = (int*)p; p += (size_t)NPAD * 4;
    int* offsets = (int*)p; p += (size_t)NPAD * 4;
    int* cursor  = (int*)p; p += (size_t)NPAD * 4;
    int* elist   = (int*)p; p += (size_t)N_EDGES * 4;
    int* partial = (int*)p;  // 256 ints

    hipMemsetAsync(count,  0, NPAD * sizeof(int), stream);
    hipMemsetAsync(cursor, 0, NPAD * sizeof(int), stream);

    // Stage 1: feature projections -> xcat (X0), then x1 = lrelu(xcat@W_in+b) (X1)
    proj768_v3<25><<<NPAD / 64, 256, 0, stream>>>(des, Wd, bd, 0,  X0);
    proj768_v3<28><<<NPAD / 64, 256, 0, stream>>>(tw,  Wt, bt, 25, X0);
    small_proj_kernel<<<(N_NODES * 75 + 255) / 256, 256, 0, stream>>>(
        nump, catp, newf, Wn, bn, Wc, bc, Ww, bw, X0);
    gemm_v2<128, false, true><<<NPAD / 128, 256, 0, stream>>>(
        X0, nullptr, Win, nullptr, bin, X1);

    // CSR build (once, reused by both RGCN layers)
    count_kernel<<<(N_EDGES + 255) / 256, 256, 0, stream>>>(ei, count);
    scan1_kernel<<<NBLK_SCAN, 256, 0, stream>>>(count, partial);
    scan2_kernel<<<1, 256, 0, stream>>>(partial);
    scan3_kernel<<<NBLK_SCAN, 256, 0, stream>>>(count, partial, offsets);
    fill_kernel<<<(N_EDGES + 255) / 256, 256, 0, stream>>>(ei, et, offsets, cursor, elist);

    // RGCN layer 1: aggregate x1 -> S; x2 = [S|x1] @ [rel_w1; root_w1] + bias1 (X0)
    aggregate_v3<<<(N_NODES + 7) / 8, 256, 0, stream>>>(X1, offsets, count, elist, S);
    gemm_v2<384, true, false><<<NPAD / 128, 256, 0, stream>>>(
        S, X1, relw1, rootw1, bias1, X0);

    // RGCN layer 2: aggregate x2 -> S; x3 = [S|x2] @ [rel_w2; root_w2] + bias2 (X1)
    aggregate_v3<<<(N_NODES + 7) / 8, 256, 0, stream>>>(X0, offsets, count, elist, S);
    gemm_v2<384, true, false><<<NPAD / 128, 256, 0, stream>>>(
        S, X0, relw2, rootw2, bias2, X1);

    // Output head: x4 = lrelu(x3@W_out1+b) (X0); out = x4@W_out2+b
    gemm_v2<128, false, true><<<NPAD / 128, 256, 0, stream>>>(
        X1, nullptr, Wo1, nullptr, bo1, X0);
    final_kernel<<<N_NODES, 64, 0, stream>>>(X0, Wo2, bo2, outp);
}

// Round 4
// 881.497 us; speedup vs baseline: 1.2633x; 1.2633x over previous
//
#include <hip/hip_runtime.h>

// Problem constants
#define N_NODES 50000
#define N_EDGES 600000
#define NPAD    50048          // 782*64 = 391*128, padded row count for tiled GEMMs
#define NBLK_SCAN 196          // ceil(50000/256)

static __device__ __forceinline__ float lrelu(float v) {
    return v > 0.f ? v : 0.01f * v;
}

// ---------------------------------------------------------------------------
// proj768_v4: [N,768] @ [768,NCOLS] for des (NCOLS=25) and tweet (NCOLS=28)
// in ONE dispatch. Thread-per-row streaming, W wave-uniform (scalar loads).
// Split-K=4 across blockIdx.y (global fp32 partials), blockIdx.z = matrix.
// unroll 8 -> 8 float4 loads in flight per thread (MLP), 6.1 waves/SIMD (TLP).
// ---------------------------------------------------------------------------
template<int NCOLS>
__device__ __forceinline__ void proj_body(
    const float* __restrict__ A, const float* __restrict__ W,
    float* __restrict__ P, int row, int kq)
{
    float acc[NCOLS];
    #pragma unroll
    for (int c = 0; c < NCOLS; c++) acc[c] = 0.f;

    const float4* Ar = (const float4*)(A + (size_t)row * 768 + kq * 192);
    const float*  Wp = W + (size_t)kq * 192 * NCOLS;

    #pragma unroll 8
    for (int j = 0; j < 48; j++) {
        float4 a = Ar[j];
        const float* w = Wp + j * 4 * NCOLS;
        #pragma unroll
        for (int c = 0; c < NCOLS; c++)
            acc[c] += a.x * w[c] + a.y * w[NCOLS + c]
                    + a.z * w[2 * NCOLS + c] + a.w * w[3 * NCOLS + c];
    }
    float* o = P + ((size_t)kq * N_NODES + row) * 32;
    #pragma unroll
    for (int c = 0; c < NCOLS; c++) o[c] = acc[c];
}

__global__ __launch_bounds__(256) void proj768_v4(
    const float* __restrict__ des, const float* __restrict__ Wd,
    const float* __restrict__ tw,  const float* __restrict__ Wt,
    float* __restrict__ P)
{
    const int row = blockIdx.x * 256 + threadIdx.x;
    if (row >= N_NODES) return;
    const int kq = blockIdx.y;            // K quarter 0..3
    if (blockIdx.z == 0) proj_body<25>(des, Wd, P, row, kq);
    else                 proj_body<28>(tw, Wt, P + (size_t)4 * N_NODES * 32, row, kq);
}

// Combine 4 split-K partials for des (cols 0..24) + tweet (25..52),
// add bias, lrelu, store into X0.
__global__ void combine_proj4(const float* __restrict__ P,
                              const float* __restrict__ bd, const float* __restrict__ bt,
                              float* __restrict__ X0)
{
    int id = blockIdx.x * 256 + threadIdx.x;
    int n = id >> 6, c = id & 63;
    if (n >= N_NODES || c >= 53) return;
    const float* base; int cc; float b;
    if (c < 25) { base = P;                              cc = c;      b = bd[cc]; }
    else        { base = P + (size_t)4 * N_NODES * 32;   cc = c - 25; b = bt[cc]; }
    float s = base[((size_t)0 * N_NODES + n) * 32 + cc]
            + base[((size_t)1 * N_NODES + n) * 32 + cc]
            + base[((size_t)2 * N_NODES + n) * 32 + cc]
            + base[((size_t)3 * N_NODES + n) * 32 + cc];
    X0[(size_t)n * 128 + c] = lrelu(s + b);
}

// ---------------------------------------------------------------------------
// Small projections: num (K=7 -> cols 53..77), cat (K=11 -> 78..102),
// new_feature (K=1 -> 103..127). One thread per (node, out-col).
// ---------------------------------------------------------------------------
__global__ void small_proj_kernel(
    const float* __restrict__ nump, const float* __restrict__ catp, const float* __restrict__ newf,
    const float* __restrict__ Wn, const float* __restrict__ bn,
    const float* __restrict__ Wc, const float* __restrict__ bc,
    const float* __restrict__ Ww, const float* __restrict__ bw,
    float* __restrict__ out)
{
    int id = blockIdx.x * 256 + threadIdx.x;
    int n = id / 75, c = id % 75;
    if (n >= N_NODES) return;
    float acc; int col;
    if (c < 25) {
        col = 53 + c; acc = bn[c];
        #pragma unroll
        for (int k = 0; k < 7; k++) acc += nump[n * 7 + k] * Wn[k * 25 + c];
    } else if (c < 50) {
        int cc = c - 25; col = 78 + cc; acc = bc[cc];
        #pragma unroll
        for (int k = 0; k < 11; k++) acc += catp[n * 11 + k] * Wc[k * 25 + cc];
    } else {
        int cc = c - 50; col = 103 + cc;
        acc = bw[cc] + newf[n] * Ww[cc];
    }
    out[(size_t)n * 128 + col] = lrelu(acc);
}

// ---------------------------------------------------------------------------
// gemm_v2: tiled fp32 GEMM, 128 out cols. Tile 128 rows x 128 cols, K-tile 32.
// 256 threads as 16x16, 8x8 micro-tile. A stored TRANSPOSED in LDS so the
// inner loop is pure ds_read_b128.
// SPLIT: A = [S (256 wide) | A2 (128 wide)], B = [rel_w (256 rows); root_w].
// ---------------------------------------------------------------------------
template<int KTOT, bool SPLIT, bool ACT>
__global__ __launch_bounds__(256, 4) void gemm_v2(
    const float* __restrict__ A, const float* __restrict__ A2,
    const float* __restrict__ B, const float* __restrict__ B2,
    const float* __restrict__ bias, float* __restrict__ out)
{
    __shared__ float AlT[32 * 132];   // [k][row], row-padded stride 132
    __shared__ float Bl [32 * 132];   // [k][col]
    const int t  = threadIdx.x;
    const int r0 = blockIdx.x * 128;
    const int tx = t & 15, ty = t >> 4;

    float acc[8][8] = {};

    for (int k0 = 0; k0 < KTOT; k0 += 32) {
        // A tile: 128 rows x 32 k = 1024 float4, 4 per thread, store transposed
        #pragma unroll
        for (int i = 0; i < 4; i++) {
            int f4i = t + i * 256;
            int row = f4i >> 3, c4 = f4i & 7;
            int k = k0 + c4 * 4;
            float4 v;
            if (!SPLIT) {
                v = *(const float4*)&A[(size_t)(r0 + row) * 128 + k];
            } else {
                if (k < 256) v = *(const float4*)&A[(size_t)(r0 + row) * 256 + k];
                else         v = *(const float4*)&A2[(size_t)(r0 + row) * 128 + (k - 256)];
            }
            AlT[(c4 * 4 + 0) * 132 + row] = v.x;
            AlT[(c4 * 4 + 1) * 132 + row] = v.y;
            AlT[(c4 * 4 + 2) * 132 + row] = v.z;
            AlT[(c4 * 4 + 3) * 132 + row] = v.w;
        }
        // B tile: 32 k x 128 cols = 1024 float4, 4 per thread
        #pragma unroll
        for (int i = 0; i < 4; i++) {
            int f4i = t + i * 256;
            int kk = f4i >> 5, c4 = f4i & 31;
            int k = k0 + kk;
            float4 v;
            if (!SPLIT) v = *(const float4*)&B[(size_t)k * 128 + c4 * 4];
            else v = (k < 256) ? *(const float4*)&B[(size_t)k * 128 + c4 * 4]
                               : *(const float4*)&B2[(size_t)(k - 256) * 128 + c4 * 4];
            *(float4*)&Bl[kk * 132 + c4 * 4] = v;
        }
        __syncthreads();
        #pragma unroll 4
        for (int k = 0; k < 32; k++) {
            float4 a0 = *(const float4*)&AlT[k * 132 + ty * 8];
            float4 a1 = *(const float4*)&AlT[k * 132 + ty * 8 + 4];
            float4 b0 = *(const float4*)&Bl [k * 132 + tx * 8];
            float4 b1 = *(const float4*)&Bl [k * 132 + tx * 8 + 4];
            float av[8] = {a0.x, a0.y, a0.z, a0.w, a1.x, a1.y, a1.z, a1.w};
            float bv[8] = {b0.x, b0.y, b0.z, b0.w, b1.x, b1.y, b1.z, b1.w};
            #pragma unroll
            for (int i = 0; i < 8; i++)
                #pragma unroll
                for (int j = 0; j < 8; j++) acc[i][j] += av[i] * bv[j];
        }
        __syncthreads();
    }
    float4 bb0 = *(const float4*)&bias[tx * 8];
    float4 bb1 = *(const float4*)&bias[tx * 8 + 4];
    float bb[8] = {bb0.x, bb0.y, bb0.z, bb0.w, bb1.x, bb1.y, bb1.z, bb1.w};
    #pragma unroll
    for (int i = 0; i < 8; i++) {
        size_t row = (size_t)(r0 + ty * 8 + i);
        float o[8];
        #pragma unroll
        for (int j = 0; j < 8; j++) {
            o[j] = acc[i][j] + bb[j];
            if (ACT) o[j] = lrelu(o[j]);
        }
        *(float4*)&out[row * 128 + tx * 8]     = make_float4(o[0], o[1], o[2], o[3]);
        *(float4*)&out[row * 128 + tx * 8 + 4] = make_float4(o[4], o[5], o[6], o[7]);
    }
}

// ---------------------------------------------------------------------------
// CSR build: count, 3-phase exclusive scan, fill (type packed into sign bit).
// ---------------------------------------------------------------------------
__global__ void count_kernel(const int* __restrict__ ei, int* __restrict__ count) {
    int e = blockIdx.x * 256 + threadIdx.x;
    if (e < N_EDGES) atomicAdd(&count[ei[N_EDGES + e]], 1);
}

__global__ void scan1_kernel(const int* __restrict__ count, int* __restrict__ partial) {
    __shared__ int sm[256];
    int b = blockIdx.x, t = threadIdx.x;
    int i = b * 256 + t;
    sm[t] = (i < N_NODES) ? count[i] : 0;
    __syncthreads();
    for (int off = 128; off > 0; off >>= 1) {
        if (t < off) sm[t] += sm[t + off];
        __syncthreads();
    }
    if (t == 0) partial[b] = sm[0];
}

__global__ void scan2_kernel(int* __restrict__ partial) {
    __shared__ int sm[256];
    int t = threadIdx.x;
    int v = (t < NBLK_SCAN) ? partial[t] : 0;
    sm[t] = v; __syncthreads();
    for (int off = 1; off < 256; off <<= 1) {
        int add = (t >= off) ? sm[t - off] : 0;
        __syncthreads();
        sm[t] += add;
        __syncthreads();
    }
    partial[t] = sm[t] - v;   // exclusive
}

__global__ void scan3_kernel(const int* __restrict__ count, const int* __restrict__ partial,
                             int* __restrict__ offsets) {
    __shared__ int sm[256];
    int b = blockIdx.x, t = threadIdx.x;
    int i = b * 256 + t;
    int v = (i < N_NODES) ? count[i] : 0;
    sm[t] = v; __syncthreads();
    for (int off = 1; off < 256; off <<= 1) {
        int add = (t >= off) ? sm[t - off] : 0;
        __syncthreads();
        sm[t] += add;
        __syncthreads();
    }
    if (i < N_NODES) offsets[i] = partial[b] + sm[t] - v;
}

__global__ void fill_kernel(const int* __restrict__ ei, const int* __restrict__ et,
                            const int* __restrict__ offsets, int* __restrict__ cursor,
                            int* __restrict__ elist) {
    int e = blockIdx.x * 256 + threadIdx.x;
    if (e < N_EDGES) {
        int d = ei[N_EDGES + e];
        int pos = atomicAdd(&cursor[d], 1);
        elist[offsets[d] + pos] = (int)(((unsigned)ei[e]) | (((unsigned)et[e]) << 31));
    }
}

// ---------------------------------------------------------------------------
// aggregate_v3: s[n][r][:] = (1/max(deg,1)) * sum_{e:type=r} x[src_e][:]
// 32 lanes per node (float4 each), 8 nodes per 256-thread block.
// 2-edge unroll for memory-level parallelism.
// ---------------------------------------------------------------------------
__global__ __launch_bounds__(256) void aggregate_v3(
    const float* __restrict__ x, const int* __restrict__ offsets,
    const int* __restrict__ count, const int* __restrict__ elist,
    float* __restrict__ s)
{
    int nid  = blockIdx.x * 8 + (threadIdx.x >> 5);
    int lane = threadIdx.x & 31;
    if (nid >= N_NODES) return;
    int start = offsets[nid], dg = count[nid];
    float4 a0 = make_float4(0.f, 0.f, 0.f, 0.f);
    float4 a1 = make_float4(0.f, 0.f, 0.f, 0.f);
    int i = 0;
    for (; i + 2 <= dg; i += 2) {
        int v0 = elist[start + i];
        int v1 = elist[start + i + 1];
        float4 u = ((const float4*)&x[(size_t)(v0 & 0x7FFFFFFF) * 128])[lane];
        float4 w = ((const float4*)&x[(size_t)(v1 & 0x7FFFFFFF) * 128])[lane];
        if (v0 < 0) { a1.x += u.x; a1.y += u.y; a1.z += u.z; a1.w += u.w; }
        else        { a0.x += u.x; a0.y += u.y; a0.z += u.z; a0.w += u.w; }
        if (v1 < 0) { a1.x += w.x; a1.y += w.y; a1.z += w.z; a1.w += w.w; }
        else        { a0.x += w.x; a0.y += w.y; a0.z += w.z; a0.w += w.w; }
    }
    if (i < dg) {
        int v0 = elist[start + i];
        float4 u = ((const float4*)&x[(size_t)(v0 & 0x7FFFFFFF) * 128])[lane];
        if (v0 < 0) { a1.x += u.x; a1.y += u.y; a1.z += u.z; a1.w += u.w; }
        else        { a0.x += u.x; a0.y += u.y; a0.z += u.z; a0.w += u.w; }
    }
    float inv = 1.0f / (float)(dg > 0 ? dg : 1);
    a0.x *= inv; a0.y *= inv; a0.z *= inv; a0.w *= inv;
    a1.x *= inv; a1.y *= inv; a1.z *= inv; a1.w *= inv;
    ((float4*)&s[(size_t)nid * 256])[lane]       = a0;
    ((float4*)&s[(size_t)nid * 256 + 128])[lane] = a1;
}

// ---------------------------------------------------------------------------
// Final: out[n][0:2] = x4[n] @ W_out2 + b_out2. One wave per node.
// ---------------------------------------------------------------------------
__global__ __launch_bounds__(64) void final_kernel(
    const float* __restrict__ x, const float* __restrict__ W2,
    const float* __restrict__ b2, float* __restrict__ out)
{
    int n = blockIdx.x;
    int t = threadIdx.x;
    float x0 = x[(size_t)n * 128 + t];
    float x1 = x[(size_t)n * 128 + 64 + t];
    float p0 = x0 * W2[t * 2]     + x1 * W2[(t + 64) * 2];
    float p1 = x0 * W2[t * 2 + 1] + x1 * W2[(t + 64) * 2 + 1];
    #pragma unroll
    for (int off = 32; off > 0; off >>= 1) {
        p0 += __shfl_down(p0, off);
        p1 += __shfl_down(p1, off);
    }
    if (t == 0) {
        out[(size_t)n * 2]     = p0 + b2[0];
        out[(size_t)n * 2 + 1] = p1 + b2[1];
    }
}

// ---------------------------------------------------------------------------
extern "C" void kernel_launch(void* const* d_in, const int* in_sizes, int n_in,
                              void* d_out, int out_size, void* d_ws, size_t ws_size,
                              hipStream_t stream)
{
    const float* des   = (const float*)d_in[0];
    const float* tw    = (const float*)d_in[1];
    const float* nump  = (const float*)d_in[2];
    const float* catp  = (const float*)d_in[3];
    const float* newf  = (const float*)d_in[4];
    const int*   ei    = (const int*)d_in[5];
    const int*   et    = (const int*)d_in[6];
    const float* Wd    = (const float*)d_in[7];  const float* bd  = (const float*)d_in[8];
    const float* Wt    = (const float*)d_in[9];  const float* bt  = (const float*)d_in[10];
    const float* Wn    = (const float*)d_in[11]; const float* bn  = (const float*)d_in[12];
    const float* Wc    = (const float*)d_in[13]; const float* bc  = (const float*)d_in[14];
    const float* Ww    = (const float*)d_in[15]; const float* bw  = (const float*)d_in[16];
    const float* Win   = (const float*)d_in[17]; const float* bin = (const float*)d_in[18];
    const float* relw1 = (const float*)d_in[19]; const float* rootw1 = (const float*)d_in[20];
    const float* bias1 = (const float*)d_in[21];
    const float* relw2 = (const float*)d_in[22]; const float* rootw2 = (const float*)d_in[23];
    const float* bias2 = (const float*)d_in[24];
    const float* Wo1   = (const float*)d_in[25]; const float* bo1 = (const float*)d_in[26];
    const float* Wo2   = (const float*)d_in[27]; const float* bo2 = (const float*)d_in[28];
    float* outp = (float*)d_out;

    // Workspace layout (~106 MB)
    char* ws = (char*)d_ws;
    const size_t szX = (size_t)NPAD * 128 * sizeof(float);
    float* X0 = (float*)(ws);
    float* X1 = (float*)(ws + szX);
    float* S  = (float*)(ws + 2 * szX);          // NPAD*256 floats (51.25 MB)
    // P (proj partials: 2 matrices x 4 K-quarters x N x 32 = 51.2 MB) aliases S;
    // P is dead before the first aggregate writes S.
    float* P  = S;
    char* p = ws + 2 * szX + (size_t)NPAD * 256 * sizeof(float);
    int* count   = (int*)p; p += (size_t)NPAD * 4;
    int* offsets = (int*)p; p += (size_t)NPAD * 4;
    int* cursor  = (int*)p; p += (size_t)NPAD * 4;
    int* elist   = (int*)p; p += (size_t)N_EDGES * 4;
    int* partial = (int*)p;  // 256 ints

    hipMemsetAsync(count,  0, NPAD * sizeof(int), stream);
    hipMemsetAsync(cursor, 0, NPAD * sizeof(int), stream);

    // Stage 1: feature projections -> xcat (X0), then x1 = lrelu(xcat@W_in+b) (X1)
    dim3 pg((N_NODES + 255) / 256, 4, 2);
    proj768_v4<<<pg, 256, 0, stream>>>(des, Wd, tw, Wt, P);
    small_proj_kernel<<<(N_NODES * 75 + 255) / 256, 256, 0, stream>>>(
        nump, catp, newf, Wn, bn, Wc, bc, Ww, bw, X0);
    combine_proj4<<<(N_NODES * 64 + 255) / 256, 256, 0, stream>>>(P, bd, bt, X0);
    gemm_v2<128, false, true><<<NPAD / 128, 256, 0, stream>>>(
        X0, nullptr, Win, nullptr, bin, X1);

    // CSR build (once, reused by both RGCN layers)
    count_kernel<<<(N_EDGES + 255) / 256, 256, 0, stream>>>(ei, count);
    scan1_kernel<<<NBLK_SCAN, 256, 0, stream>>>(count, partial);
    scan2_kernel<<<1, 256, 0, stream>>>(partial);
    scan3_kernel<<<NBLK_SCAN, 256, 0, stream>>>(count, partial, offsets);
    fill_kernel<<<(N_EDGES + 255) / 256, 256, 0, stream>>>(ei, et, offsets, cursor, elist);

    // RGCN layer 1: aggregate x1 -> S; x2 = [S|x1] @ [rel_w1; root_w1] + bias1 (X0)
    aggregate_v3<<<(N_NODES + 7) / 8, 256, 0, stream>>>(X1, offsets, count, elist, S);
    gemm_v2<384, true, false><<<NPAD / 128, 256, 0, stream>>>(
        S, X1, relw1, rootw1, bias1, X0);

    // RGCN layer 2: aggregate x2 -> S; x3 = [S|x2] @ [rel_w2; root_w2] + bias2 (X1)
    aggregate_v3<<<(N_NODES + 7) / 8, 256, 0, stream>>>(X0, offsets, count, elist, S);
    gemm_v2<384, true, false><<<NPAD / 128, 256, 0, stream>>>(
        S, X0, relw2, rootw2, bias2, X1);

    // Output head: x4 = lrelu(x3@W_out1+b) (X0); out = x4@W_out2+b
    gemm_v2<128, false, true><<<NPAD / 128, 256, 0, stream>>>(
        X1, nullptr, Wo1, nullptr, bo1, X0);
    final_kernel<<<N_NODES, 64, 0, stream>>>(X0, Wo2, bo2, outp);
}